// Round 1
// baseline (487.898 us; speedup 1.0000x reference)
//
#include <hip/hip_runtime.h>
#include <hip/hip_bf16.h>

#define BB 8
#define CC 256
#define HH 64
#define WW 64
#define MM 512
#define HWHW 4096

// ---------------- K1: I_G = mean over H,W ----------------
__global__ void k_ig(const float* __restrict__ img, float* __restrict__ IG) {
    int bc = blockIdx.x;                       // 0..2047  (b*C + c)
    const float4* p = (const float4*)(img + (size_t)bc * HWHW);
    int t = threadIdx.x;
    float s = 0.f;
#pragma unroll
    for (int k = 0; k < 4; k++) {
        float4 v = p[t + 256 * k];
        s += v.x + v.y + v.z + v.w;
    }
#pragma unroll
    for (int off = 32; off > 0; off >>= 1) s += __shfl_down(s, off);
    __shared__ float red[4];
    int wave = t >> 6, lane = t & 63;
    if (lane == 0) red[wave] = s;
    __syncthreads();
    if (t == 0) IG[bc] = (red[0] + red[1] + red[2] + red[3]) * (1.f / 4096.f);
}

// ---------------- K2: global path -> gate g = sigmoid(softmax(IG@M^T)@M + IG) ----------------
__global__ void k_global(const float* __restrict__ IG, const float* __restrict__ mem,
                         float* __restrict__ g) {
    int b = blockIdx.x;
    int t = threadIdx.x;
    __shared__ float ig[CC];
    __shared__ float sc[MM];
    __shared__ float red[256];
    ig[t] = IG[b * CC + t];
    __syncthreads();
    for (int m = t; m < MM; m += 256) {
        const float* mr = mem + (size_t)m * CC;
        float s = 0.f;
#pragma unroll 4
        for (int c = 0; c < CC; c++) s = fmaf(mr[c], ig[c], s);
        sc[m] = s;
    }
    __syncthreads();
    // max reduce over 512
    red[t] = fmaxf(sc[t], sc[t + 256]);
    __syncthreads();
    for (int o = 128; o > 0; o >>= 1) {
        if (t < o) red[t] = fmaxf(red[t], red[t + o]);
        __syncthreads();
    }
    float mx = red[0];
    __syncthreads();
    float e0 = expf(sc[t] - mx), e1 = expf(sc[t + 256] - mx);
    sc[t] = e0; sc[t + 256] = e1;           // each thread touches only its own 2 slots
    red[t] = e0 + e1;
    __syncthreads();
    for (int o = 128; o > 0; o >>= 1) {
        if (t < o) red[t] += red[t + o];
        __syncthreads();
    }
    float inv = 1.f / red[0];
    // resp for channel c = t  (coalesced across t)
    float r = ig[t];
    for (int m = 0; m < MM; m++) r = fmaf(sc[m] * inv, mem[(size_t)m * CC + t], r);
    g[b * CC + t] = 1.f / (1.f + expf(-r));
}

// ---------------- K3: memT[c][m] = memory[m][c] ----------------
__global__ void k_memT(const float* __restrict__ mem, float* __restrict__ memT) {
    int i = blockIdx.x * 256 + threadIdx.x;    // 131072
    int c = i >> 9, m = i & 511;
    memT[i] = mem[m * CC + c];
}

// ---------------- K4: mf[m][o] = sum_c memory[m][c] * fusion_w[o][256+c] ----------------
__global__ void k_mf(const float* __restrict__ mem, const float* __restrict__ fw,
                     float* __restrict__ mf) {
    int m0 = blockIdx.x * 8;                   // grid 64
    int t = threadIdx.x;                       // o
    __shared__ float mrow[8][CC];
#pragma unroll
    for (int j = 0; j < 8; j++) mrow[j][t] = mem[(size_t)(m0 + j) * CC + t];
    __syncthreads();
    const float* fwr = fw + (size_t)t * (2 * CC) + CC;
    float acc[8];
#pragma unroll
    for (int j = 0; j < 8; j++) acc[j] = 0.f;
#pragma unroll 4
    for (int c = 0; c < CC; c++) {
        float f = fwr[c];
#pragma unroll
        for (int j = 0; j < 8; j++) acc[j] = fmaf(mrow[j][c], f, acc[j]);
    }
#pragma unroll
    for (int j = 0; j < 8; j++) mf[(size_t)(m0 + j) * CC + t] = acc[j];
}

// ---------------- K5: Wg[b][c][o] = g[b][c] * fusion_w[o][c] ----------------
__global__ void k_wg(const float* __restrict__ g, const float* __restrict__ fw,
                     float* __restrict__ Wg) {
    int i = blockIdx.x * 256 + threadIdx.x;    // 524288
    int o = i & 255, c = (i >> 8) & 255, b = i >> 16;
    Wg[i] = g[b * CC + c] * fw[o * (2 * CC) + c];
}

// ---------------- K6: main fused kernel ----------------
// grid 512 = B*H ; block 256 (4 waves); one image row (64 pixels) per block.
// phase2: scores[512 x 64] fp32 + per-pixel top2 ; phase3: gated fusion GEMM + epilogue
#define MBLK 8
__global__ __launch_bounds__(256, 2) void k_main(
        const float* __restrict__ img, const float* __restrict__ memT,
        const float* __restrict__ Wg, const float* __restrict__ mf,
        const float* __restrict__ fb, float* __restrict__ xbuf) {
    int bh = blockIdx.x;
    int b = bh >> 6, h = bh & 63;
    int t = threadIdx.x;
    int wave = __builtin_amdgcn_readfirstlane(t) >> 6;   // uniform -> scalar loads below
    int lane = t & 63;                                   // pixel (w coordinate)
    __shared__ float Xs[CC][64];                         // 64 KB
    __shared__ float mvv[4][64][2];
    __shared__ int   mii[4][64][2];

    // stage X tile [256 c][64 w]
    const float* src = img + (size_t)b * CC * HWHW + h * 64;
#pragma unroll
    for (int pass = 0; pass < 16; pass++) {
        int c = pass * 16 + (t >> 4);
        int w4 = (t & 15) * 4;
        float4 v = *(const float4*)(src + (size_t)c * HWHW + w4);
        *(float4*)&Xs[c][w4] = v;
    }
    __syncthreads();

    // ---- phase 2: scores + per-wave top2 (wave handles m in [wave*128, wave*128+128)) ----
    float v0 = -1e30f, v1 = -1e30f;
    int i0 = 0, i1 = 0;
    for (int it = 0; it < 128 / MBLK; it++) {
        int m0 = wave * 128 + it * MBLK;
        float acc[MBLK];
#pragma unroll
        for (int j = 0; j < MBLK; j++) acc[j] = 0.f;
#pragma unroll 4
        for (int c = 0; c < CC; c++) {
            float x = Xs[c][lane];
            const float* mt = memT + c * MM + m0;        // wave-uniform -> s_load
#pragma unroll
            for (int j = 0; j < MBLK; j++) acc[j] = fmaf(mt[j], x, acc[j]);
        }
#pragma unroll
        for (int j = 0; j < MBLK; j++) {
            float s = acc[j];
            int m = m0 + j;
            if (s > v0) { v1 = v0; i1 = i0; v0 = s; i0 = m; }
            else if (s > v1) { v1 = s; i1 = m; }
        }
    }
    mvv[wave][lane][0] = v0; mvv[wave][lane][1] = v1;
    mii[wave][lane][0] = i0; mii[wave][lane][1] = i1;
    __syncthreads();

    // merge 4 waves' top2 (ascending wave = ascending m => stable tie-break like lax.top_k)
    float tv0 = -1e30f, tv1 = -1e30f;
    int ti0 = 0, ti1 = 0;
#pragma unroll
    for (int wv = 0; wv < 4; wv++) {
#pragma unroll
        for (int k2 = 0; k2 < 2; k2++) {
            float s = mvv[wv][lane][k2];
            int m = mii[wv][lane][k2];
            if (s > tv0) { tv1 = tv0; ti1 = ti0; tv0 = s; ti0 = m; }
            else if (s > tv1) { tv1 = s; ti1 = m; }
        }
    }
    float e1 = expf(tv1 - tv0);
    float a0 = 1.f / (1.f + e1);
    float a1 = e1 * a0;

    // ---- phase 3: x[o][p] = sum_c Wg[b][c][o]*X[c][p] + a0*mf[i0][o] + a1*mf[i1][o] + fb[o] ----
    const float* WgB = Wg + (size_t)b * CC * CC;
    for (int it = 0; it < 64 / MBLK; it++) {
        int o0 = wave * 64 + it * MBLK;
        float acc[MBLK];
#pragma unroll
        for (int j = 0; j < MBLK; j++) acc[j] = 0.f;
#pragma unroll 4
        for (int c = 0; c < CC; c++) {
            float x = Xs[c][lane];
            const float* wr = WgB + c * CC + o0;         // wave-uniform -> s_load
#pragma unroll
            for (int j = 0; j < MBLK; j++) acc[j] = fmaf(wr[j], x, acc[j]);
        }
        const float* mf0 = mf + (size_t)ti0 * CC + o0;   // per-lane gather (L2-resident)
        const float* mf1 = mf + (size_t)ti1 * CC + o0;
#pragma unroll
        for (int j = 0; j < MBLK; j++) {
            float val = acc[j] + a0 * mf0[j] + a1 * mf1[j] + fb[o0 + j];
            val = val > 0.f ? val : 0.2f * val;
            xbuf[((size_t)b * CC + (o0 + j)) * HWHW + h * 64 + lane] = val;
        }
    }
}

// ---------------- K7: depthwise dilated 3x3 (d=2) + bias + leaky ----------------
__global__ void k_dw(const float* __restrict__ x, const float* __restrict__ dw,
                     const float* __restrict__ db, float* __restrict__ out) {
    int bc = blockIdx.x;                       // 0..2047
    int c = bc & 255;
    __shared__ float plane[HWHW];              // 16 KB
    const float4* src = (const float4*)(x + (size_t)bc * HWHW);
    int t = threadIdx.x;
#pragma unroll
    for (int k = 0; k < 4; k++) ((float4*)plane)[t + 256 * k] = src[t + 256 * k];
    __syncthreads();
    float w[9];
#pragma unroll
    for (int j = 0; j < 9; j++) w[j] = dw[c * 9 + j];
    float bias = db[c];
    float* dst = out + (size_t)bc * HWHW;
#pragma unroll
    for (int k = 0; k < 16; k++) {
        int p = t + 256 * k;
        int hh = p >> 6, ww = p & 63;
        float s = bias;
#pragma unroll
        for (int u = 0; u < 3; u++) {
            int h2 = hh + 2 * (u - 1);
            if ((unsigned)h2 < 64u) {
#pragma unroll
                for (int v = 0; v < 3; v++) {
                    int w2 = ww + 2 * (v - 1);
                    if ((unsigned)w2 < 64u) s = fmaf(plane[h2 * 64 + w2], w[u * 3 + v], s);
                }
            }
        }
        dst[p] = s > 0.f ? s : 0.2f * s;
    }
}

extern "C" void kernel_launch(void* const* d_in, const int* in_sizes, int n_in,
                              void* d_out, int out_size, void* d_ws, size_t ws_size,
                              hipStream_t stream) {
    const float* img = (const float*)d_in[0];
    const float* mem = (const float*)d_in[1];
    const float* fw  = (const float*)d_in[2];
    const float* fb  = (const float*)d_in[3];
    const float* dw  = (const float*)d_in[4];
    const float* db  = (const float*)d_in[5];
    float* out = (float*)d_out;
    float* ws = (float*)d_ws;

    float* IG   = ws;                 // 2048
    float* g    = ws + 2048;          // 2048
    float* memT = ws + 4096;          // 131072
    float* mf   = ws + 135168;        // 131072
    float* Wg   = ws + 266240;        // 524288
    float* xb   = ws + 790528;        // 8388608  (total ~36.7 MB)

    k_ig    <<<BB * CC,        256, 0, stream>>>(img, IG);
    k_memT  <<<MM * CC / 256,  256, 0, stream>>>(mem, memT);
    k_mf    <<<MM / 8,         256, 0, stream>>>(mem, fw, mf);
    k_global<<<BB,             256, 0, stream>>>(IG, mem, g);
    k_wg    <<<BB * CC,        256, 0, stream>>>(g, fw, Wg);
    k_main  <<<BB * HH,        256, 0, stream>>>(img, memT, Wg, mf, fb, xb);
    k_dw    <<<BB * CC,        256, 0, stream>>>(xb, dw, db, out);
}

// Round 2
// 263.084 us; speedup vs baseline: 1.8545x; 1.8545x over previous
//
#include <hip/hip_runtime.h>
#include <hip/hip_bf16.h>

#define BB 8
#define CC 256
#define HH 64
#define WW 64
#define MM 512
#define HWHW 4096

typedef __attribute__((ext_vector_type(4))) float f32x4;
typedef __attribute__((ext_vector_type(8))) short s16x8;

static __device__ __forceinline__ ushort f2bf(float f) {
    unsigned u = __float_as_uint(f);
    unsigned r = ((u >> 16) & 1u) + 0x7fffu;      // RNE
    return (ushort)((u + r) >> 16);
}

// ---------------- K1: I_G = mean over H,W ----------------
__global__ void k_ig(const float* __restrict__ img, float* __restrict__ IG) {
    int bc = blockIdx.x;                       // 0..2047  (b*C + c)
    const float4* p = (const float4*)(img + (size_t)bc * HWHW);
    int t = threadIdx.x;
    float s = 0.f;
#pragma unroll
    for (int k = 0; k < 4; k++) {
        float4 v = p[t + 256 * k];
        s += v.x + v.y + v.z + v.w;
    }
#pragma unroll
    for (int off = 32; off > 0; off >>= 1) s += __shfl_down(s, off);
    __shared__ float red[4];
    int wave = t >> 6, lane = t & 63;
    if (lane == 0) red[wave] = s;
    __syncthreads();
    if (t == 0) IG[bc] = (red[0] + red[1] + red[2] + red[3]) * (1.f / 4096.f);
}

// ---------------- K2: gate g = sigmoid(softmax(IG@M^T)@M + IG) ----------------
__global__ void k_global(const float* __restrict__ IG, const float* __restrict__ mem,
                         float* __restrict__ g) {
    int b = blockIdx.x;
    int t = threadIdx.x;
    __shared__ float ig[CC];
    __shared__ float sc[MM];
    __shared__ float red[256];
    ig[t] = IG[b * CC + t];
    __syncthreads();
    for (int m = t; m < MM; m += 256) {
        const float* mr = mem + (size_t)m * CC;
        float s = 0.f;
#pragma unroll 4
        for (int c = 0; c < CC; c++) s = fmaf(mr[c], ig[c], s);
        sc[m] = s;
    }
    __syncthreads();
    red[t] = fmaxf(sc[t], sc[t + 256]);
    __syncthreads();
    for (int o = 128; o > 0; o >>= 1) {
        if (t < o) red[t] = fmaxf(red[t], red[t + o]);
        __syncthreads();
    }
    float mx = red[0];
    __syncthreads();
    float e0 = expf(sc[t] - mx), e1 = expf(sc[t + 256] - mx);
    sc[t] = e0; sc[t + 256] = e1;
    red[t] = e0 + e1;
    __syncthreads();
    for (int o = 128; o > 0; o >>= 1) {
        if (t < o) red[t] += red[t + o];
        __syncthreads();
    }
    float inv = 1.f / red[0];
    float r = ig[t];
    for (int m = 0; m < MM; m++) r = fmaf(sc[m] * inv, mem[(size_t)m * CC + t], r);
    g[b * CC + t] = 1.f / (1.f + expf(-r));
}

// ---------------- K3: membf[m][c] = bf16(memory[m][c]) ----------------
__global__ void k_prep(const float* __restrict__ mem, ushort* __restrict__ membf) {
    int i = (blockIdx.x * 256 + threadIdx.x) * 4;     // grid 128 -> 131072 elems
    float4 v = *(const float4*)(mem + i);
    ushort4 o;
    o.x = f2bf(v.x); o.y = f2bf(v.y); o.z = f2bf(v.z); o.w = f2bf(v.w);
    *(ushort4*)(membf + i) = o;
}

// ---------------- K4: mf[m][o] = sum_c memory[m][c] * fusion_w[o][256+c] (fp32) ------
__global__ void k_mf(const float* __restrict__ mem, const float* __restrict__ fw,
                     float* __restrict__ mf) {
    int m0 = blockIdx.x * 8;                   // grid 64
    int t = threadIdx.x;                       // o
    __shared__ float mrow[8][CC];
#pragma unroll
    for (int j = 0; j < 8; j++) mrow[j][t] = mem[(size_t)(m0 + j) * CC + t];
    __syncthreads();
    const float* fwr = fw + (size_t)t * (2 * CC) + CC;
    float acc[8];
#pragma unroll
    for (int j = 0; j < 8; j++) acc[j] = 0.f;
#pragma unroll 4
    for (int c = 0; c < CC; c++) {
        float f = fwr[c];
#pragma unroll
        for (int j = 0; j < 8; j++) acc[j] = fmaf(mrow[j][c], f, acc[j]);
    }
#pragma unroll
    for (int j = 0; j < 8; j++) mf[(size_t)(m0 + j) * CC + t] = acc[j];
}

// ---------------- K5: Wgbf[b][o][c] = bf16(g[b][c] * fusion_w[o][c]) ----------------
__global__ void k_wgbf(const float* __restrict__ g, const float* __restrict__ fw,
                       ushort* __restrict__ Wgbf) {
    int b = blockIdx.x >> 8, o = blockIdx.x & 255;    // grid 2048
    int c = threadIdx.x;
    Wgbf[((size_t)blockIdx.x << 8) + c] = f2bf(g[(b << 8) + c] * fw[o * (2 * CC) + c]);
}

// ---------------- K6: main fused kernel (MFMA) ----------------
// grid 512 = B*H ; block 256 (4 waves); one image row (64 pixels) per block.
// wave w owns pixels [16w,16w+16). Own k-mapping: lane-group g holds k=8g..8g+7
// (same bijection on A and B => result invariant; only C/D layout must be exact:
//  col = lane&15, row = 4*(lane>>4)+reg  [verified]).
__global__ __launch_bounds__(256, 2) void k_main(
        const float* __restrict__ img, const float* __restrict__ mem,
        const ushort* __restrict__ membf, const ushort* __restrict__ Wgbf,
        const float* __restrict__ mf, const float* __restrict__ fb,
        float* __restrict__ xbuf) {
    int bh = blockIdx.x;
    int b = bh >> 6, h = bh & 63;
    int t = threadIdx.x;
    int wave = __builtin_amdgcn_readfirstlane(t) >> 6;
    int lane = t & 63;
    int pxl  = lane & 15;            // local pixel in wave tile / D col
    int g16  = lane >> 4;            // lane group (owns k = 8g..8g+7)
    int pxw  = wave * 16 + pxl;      // w coordinate 0..63

    __shared__ float Xs[CC][64];     // 64 KB fp32 tile
    __shared__ float tkv[4][16][12];
    __shared__ int   tki[4][16][12];
    __shared__ float rsv[4][16][4];

    // ---- stage X tile [256 c][64 w] (fp32) ----
    const float* src = img + (size_t)b * CC * HWHW + h * 64;
#pragma unroll
    for (int pass = 0; pass < 16; pass++) {
        int c = pass * 16 + (t >> 4);
        int w4 = (t & 15) * 4;
        *(float4*)&Xs[c][w4] = *(const float4*)(src + (size_t)c * HWHW + w4);
    }
    __syncthreads();

    // ---- build bf16 B-fragments for this wave's 16 pixels (reused by both GEMMs) ----
    s16x8 bfr[8];
#pragma unroll
    for (int ks = 0; ks < 8; ks++) {
        s16x8 v;
#pragma unroll
        for (int j = 0; j < 8; j++)
            v[j] = (short)f2bf(Xs[ks * 32 + g16 * 8 + j][pxw]);
        bfr[ks] = v;
    }

    // ---- phase A: scores D[m][px] via MFMA, per-lane top-3 over its 128 m's ----
    float v0 = -3e38f, v1 = -3e38f, v2 = -3e38f;
    int   i0 = 0, i1 = 0, i2 = 0;
#pragma unroll 2
    for (int mt = 0; mt < 32; mt++) {
        const ushort* ab = membf + ((size_t)(mt * 16 + pxl) * CC + g16 * 8);
        f32x4 acc = {0.f, 0.f, 0.f, 0.f};
#pragma unroll
        for (int ks = 0; ks < 8; ks++) {
            s16x8 af = *(const s16x8*)(ab + ks * 32);
            acc = __builtin_amdgcn_mfma_f32_16x16x32_bf16(af, bfr[ks], acc, 0, 0, 0);
        }
#pragma unroll
        for (int r = 0; r < 4; r++) {
            float s = acc[r];
            int m = mt * 16 + 4 * g16 + r;
            if (s > v2) {
                if (s > v1) {
                    if (s > v0) { v2 = v1; i2 = i1; v1 = v0; i1 = i0; v0 = s; i0 = m; }
                    else        { v2 = v1; i2 = i1; v1 = s;  i1 = m; }
                } else          { v2 = s;  i2 = m; }
            }
        }
    }
    tkv[wave][pxl][g16 * 3 + 0] = v0; tki[wave][pxl][g16 * 3 + 0] = i0;
    tkv[wave][pxl][g16 * 3 + 1] = v1; tki[wave][pxl][g16 * 3 + 1] = i1;
    tkv[wave][pxl][g16 * 3 + 2] = v2; tki[wave][pxl][g16 * 3 + 2] = i2;
    __syncthreads();

    // ---- merge 12 -> top-4 candidates (every lane of the pixel computes same list) ----
    float c0 = -3e38f, c1 = -3e38f, c2 = -3e38f, c3 = -3e38f;
    int   d0 = 0, d1 = 0, d2 = 0, d3 = 0;
#pragma unroll
    for (int q = 0; q < 12; q++) {
        float s = tkv[wave][pxl][q];
        int m = tki[wave][pxl][q];
        if (s > c3) {
            if (s > c1) {
                if (s > c0) { c3 = c2; d3 = d2; c2 = c1; d2 = d1; c1 = c0; d1 = d0; c0 = s; d0 = m; }
                else        { c3 = c2; d3 = d2; c2 = c1; d2 = d1; c1 = s;  d1 = m; }
            } else {
                if (s > c2) { c3 = c2; d3 = d2; c2 = s;  d2 = m; }
                else        { c3 = s;  d3 = m; }
            }
        }
    }

    // ---- fp32 rescore: lane-group g rescores candidate g of its pixel ----
    int cand = (g16 == 0) ? d0 : (g16 == 1) ? d1 : (g16 == 2) ? d2 : d3;
    {
        const float4* mr = (const float4*)(mem + (size_t)cand * CC);
        float sa = 0.f;
#pragma unroll 4
        for (int ci = 0; ci < 64; ci++) {
            float4 mv = mr[ci];
            sa = fmaf(Xs[ci * 4 + 0][pxw], mv.x, sa);
            sa = fmaf(Xs[ci * 4 + 1][pxw], mv.y, sa);
            sa = fmaf(Xs[ci * 4 + 2][pxw], mv.z, sa);
            sa = fmaf(Xs[ci * 4 + 3][pxw], mv.w, sa);
        }
        rsv[wave][pxl][g16] = sa;
    }
    __syncthreads();

    // ---- top-2 of the 4 rescored (fp32) -> attention weights ----
    float s0 = -3e38f, s1 = -3e38f; int b0 = 0, b1 = 0;
#pragma unroll
    for (int q = 0; q < 4; q++) {
        float s = rsv[wave][pxl][q];
        int m = (q == 0) ? d0 : (q == 1) ? d1 : (q == 2) ? d2 : d3;
        if (s > s1) {
            if (s > s0) { s1 = s0; b1 = b0; s0 = s; b0 = m; }
            else        { s1 = s;  b1 = m; }
        }
    }
    float e = expf(s1 - s0);
    float a0 = 1.f / (1.f + e);
    float a1 = e * a0;

    // ---- phase B: x[o][px] = sum_c Wgbf[b][o][c]*X[c][px] + a0*mf[b0]+a1*mf[b1]+fb ----
    const ushort* wgb = Wgbf + ((size_t)b * CC) * CC;
#pragma unroll 2
    for (int ot = 0; ot < 16; ot++) {
        const ushort* ab = wgb + ((size_t)(ot * 16 + pxl) * CC + g16 * 8);
        f32x4 acc = {0.f, 0.f, 0.f, 0.f};
#pragma unroll
        for (int ks = 0; ks < 8; ks++) {
            s16x8 af = *(const s16x8*)(ab + ks * 32);
            acc = __builtin_amdgcn_mfma_f32_16x16x32_bf16(af, bfr[ks], acc, 0, 0, 0);
        }
        int ob = ot * 16 + 4 * g16;                       // first of 4 output rows
        float4 m0v = *(const float4*)(mf + (size_t)b0 * CC + ob);
        float4 m1v = *(const float4*)(mf + (size_t)b1 * CC + ob);
        float4 fbv = *(const float4*)(fb + ob);
#pragma unroll
        for (int r = 0; r < 4; r++) {
            float mr0 = (r == 0) ? m0v.x : (r == 1) ? m0v.y : (r == 2) ? m0v.z : m0v.w;
            float mr1 = (r == 0) ? m1v.x : (r == 1) ? m1v.y : (r == 2) ? m1v.z : m1v.w;
            float fbr = (r == 0) ? fbv.x : (r == 1) ? fbv.y : (r == 2) ? fbv.z : fbv.w;
            float val = acc[r] + a0 * mr0 + a1 * mr1 + fbr;
            val = val > 0.f ? val : 0.2f * val;
            xbuf[((size_t)(b * CC + ob + r)) * HWHW + h * 64 + pxw] = val;
        }
    }
}

// ---------------- K7: depthwise dilated 3x3 (d=2) + bias + leaky ----------------
__global__ void k_dw(const float* __restrict__ x, const float* __restrict__ dw,
                     const float* __restrict__ db, float* __restrict__ out) {
    int bc = blockIdx.x;                       // 0..2047
    int c = bc & 255;
    __shared__ float plane[HWHW];
    const float4* src = (const float4*)(x + (size_t)bc * HWHW);
    int t = threadIdx.x;
#pragma unroll
    for (int k = 0; k < 4; k++) ((float4*)plane)[t + 256 * k] = src[t + 256 * k];
    __syncthreads();
    float w[9];
#pragma unroll
    for (int j = 0; j < 9; j++) w[j] = dw[c * 9 + j];
    float bias = db[c];
    float* dst = out + (size_t)bc * HWHW;
#pragma unroll
    for (int k = 0; k < 16; k++) {
        int p = t + 256 * k;
        int hh = p >> 6, ww = p & 63;
        float s = bias;
#pragma unroll
        for (int u = 0; u < 3; u++) {
            int h2 = hh + 2 * (u - 1);
            if ((unsigned)h2 < 64u) {
#pragma unroll
                for (int v = 0; v < 3; v++) {
                    int w2 = ww + 2 * (v - 1);
                    if ((unsigned)w2 < 64u) s = fmaf(plane[h2 * 64 + w2], w[u * 3 + v], s);
                }
            }
        }
        dst[p] = s > 0.f ? s : 0.2f * s;
    }
}

extern "C" void kernel_launch(void* const* d_in, const int* in_sizes, int n_in,
                              void* d_out, int out_size, void* d_ws, size_t ws_size,
                              hipStream_t stream) {
    const float* img = (const float*)d_in[0];
    const float* mem = (const float*)d_in[1];
    const float* fw  = (const float*)d_in[2];
    const float* fb  = (const float*)d_in[3];
    const float* dw  = (const float*)d_in[4];
    const float* db  = (const float*)d_in[5];
    float* out = (float*)d_out;
    float* ws = (float*)d_ws;

    float*  IG    = ws;                                   // 2048
    float*  gbuf  = ws + 2048;                            // 2048
    float*  mf    = ws + 4096;                            // 131072
    ushort* membf = (ushort*)(ws + 135168);               // 131072 u16 (=65536 f32)
    ushort* Wgbf  = (ushort*)(ws + 135168 + 65536);       // 524288 u16 (=262144 f32)
    float*  xb    = ws + 135168 + 65536 + 262144;         // 8388608 f32

    k_ig    <<<BB * CC, 256, 0, stream>>>(img, IG);
    k_prep  <<<128,     256, 0, stream>>>(mem, membf);
    k_mf    <<<MM / 8,  256, 0, stream>>>(mem, fw, mf);
    k_global<<<BB,      256, 0, stream>>>(IG, mem, gbuf);
    k_wgbf  <<<BB * CC, 256, 0, stream>>>(gbuf, fw, Wgbf);
    k_main  <<<BB * HH, 256, 0, stream>>>(img, mem, membf, Wgbf, mf, fb, xb);
    k_dw    <<<BB * CC, 256, 0, stream>>>(xb, dw, db, out);
}